// Round 7
// baseline (149.507 us; speedup 1.0000x reference)
//
#include <hip/hip_runtime.h>

// net_86698209837440: N=100000, DEG=32 (edges sorted by tgt, deg==32), D=24, NK=2, H=64.
// R14: feature-split two-pass to make the gather table L2-RESIDENT.
// Evidence: 4 structural eras (2B scatter / ganged lines / full hoist / tr-read)
// all flat at ~40us with low util everywhere => gather is bound by random
// line-request service to an L2-overflowing table (~64 MSHR x ~600cy L3 trip).
//  - pass A (gnnA): gathers xlo[N][16] bf16 (32B rows, 3.2MB <= 4MB L2/XCD),
//    computes a0/a1/sum for d0-15, writes pre-lo to ws [N][32] u16.
//  - pass B (gnnB): gathers xhi[N][8] bf16 (16B rows, 1.6MB), computes d16-23,
//    keeps hi in LDS, streams pre-lo back, runs the 48->64 MLP, writes out.
// Both passes keep the proven MFMA structure (A=kv rows 0,1 + ones row 2,
// 2x 32x32x16 over 32 edges). ei/kv staged per pass (streamed, nt-hinted).

#define NN   100000
#define DEG  32
#define EE   (NN * DEG)
#define DD   24
#define HH   64
#define NPB  32            // nodes per block; 100000 = 3125 * 32 exact
#define TPB  256
#define NPW  8             // nodes per wave

typedef __attribute__((ext_vector_type(8)))  short short8;
typedef __attribute__((ext_vector_type(16))) float float16;
typedef __attribute__((ext_vector_type(4)))  float f32x4;
typedef __attribute__((ext_vector_type(4)))  int   i32x4;
typedef __attribute__((ext_vector_type(2)))  int   i32x2;
typedef __attribute__((ext_vector_type(4)))  unsigned short u16x4;

__device__ __forceinline__ unsigned short f2bf(float f) {
    union { float f; unsigned u; } v; v.f = f;
    unsigned r = v.u + 0x7fffu + ((v.u >> 16) & 1u);   // RNE
    return (unsigned short)(r >> 16);
}

__device__ __forceinline__ float bf2f(unsigned u) {
    union { unsigned i; float f; } v; v.i = u << 16; return v.f;
}

// lo16(a) -> low half, lo16(b) -> high half, one v_perm_b32
__device__ __forceinline__ unsigned pk(unsigned a, unsigned b) {
    return __builtin_amdgcn_perm(b, a, 0x05040100u);
}

__device__ __forceinline__ short8 mk8(unsigned u0, unsigned u1, unsigned u2, unsigned u3) {
    union { unsigned u[4]; short8 s; } p;
    p.u[0] = u0; p.u[1] = u1; p.u[2] = u2; p.u[3] = u3;
    return p.s;
}

// ---- pre-pass: x fp32 [N][24] -> bf16 split tables xlo[N][16] + xhi[N][8]
__global__ void xcvt2(const float* __restrict__ x,
                      unsigned short* __restrict__ xlo,
                      unsigned short* __restrict__ xhi, int n6) {
    int c = blockIdx.x * blockDim.x + threadIdx.x;   // f32x4 chunk index
    if (c < n6) {
        const int row = c / 6;
        const int pos = c - row * 6;
        f32x4 v = __builtin_nontemporal_load(((const f32x4*)x) + c);
        u16x4 o;
        o.x = f2bf(v.x); o.y = f2bf(v.y); o.z = f2bf(v.z); o.w = f2bf(v.w);
        if (pos < 4) ((u16x4*)xlo)[row * 4 + pos] = o;
        else         ((u16x4*)xhi)[row * 2 + (pos - 4)] = o;
    }
}

// ================= pass A: lo features (d0-15), table slice 3.2MB =================
__global__ __launch_bounds__(TPB, 4) void gnnA(
    const unsigned short* __restrict__ xlo,   // [N,16] bf16 (32B rows)
    const int*            __restrict__ ei,    // [2,E]; row 0 = src
    const float*          __restrict__ kv,    // [2,E]
    unsigned short*       __restrict__ prew)  // [N,32] u16: 0-15 a0lo, 16-31 a1lo
{
    __shared__ int            ei_s[NPB * DEG];       // src*32 byte offsets
    __shared__ unsigned short kv_s[2 * NPB * DEG];
    __shared__ unsigned short xt_s[4][1024];         // per-wave [2 buf][32 e][16 f]

    const int t    = threadIdx.x;
    const int lane = t & 63;
    const int w    = t >> 6;
    const int m    = lane & 31;
    const int kh   = lane >> 5;
    const int kh8  = kh * 8;
    const int base = blockIdx.x * NPB;
    const int dcl  = (m < 16) ? m : 15;
    const char* xc = (const char*)xlo;
    const int grow = lane >> 1;          // gather row (edge 0..31)
    const int gh   = (lane & 1) * 16;    // 16B half of 32B row
    char* xt = (char*)&xt_s[w][0];

    {
        const size_t eb = (size_t)base * DEG;
        i32x4 ev = __builtin_nontemporal_load(((const i32x4*)(ei + eb)) + t);
        ev.x <<= 5; ev.y <<= 5; ev.z <<= 5; ev.w <<= 5;
        ((i32x4*)ei_s)[t] = ev;
        const f32x4 c0 = __builtin_nontemporal_load(((const f32x4*)(kv + eb)) + t);
        const f32x4 c1 = __builtin_nontemporal_load(((const f32x4*)(kv + EE + eb)) + t);
        u16x4 u0, u1;
        u0.x = f2bf(c0.x); u0.y = f2bf(c0.y); u0.z = f2bf(c0.z); u0.w = f2bf(c0.w);
        u1.x = f2bf(c1.x); u1.y = f2bf(c1.y); u1.z = f2bf(c1.z); u1.w = f2bf(c1.w);
        ((u16x4*)kv_s)[t] = u0;
        ((u16x4*)(kv_s + NPB * DEG))[t] = u1;
    }
    __syncthreads();

    const unsigned short* kvrow = kv_s + (m & 1) * (NPB * DEG);

    i32x4 G[NPW];
    unsigned xv[NPW];

    #pragma unroll
    for (int n = 0; n < NPW; ++n)
        xv[n] = xlo[(size_t)(base + w * NPW + n) * 16 + dcl];

    #pragma unroll
    for (int n = 0; n < NPW; ++n) {
        const int off = ei_s[(w * NPW + n) * DEG + grow];
        G[n] = *(const i32x4*)(xc + (unsigned)(off + gh));
    }

    #pragma unroll
    for (int n = 0; n < NPW; ++n) {
        const int b = (n & 1) * 1024;
        // write node tile: row grow at (grow*32+gh) ^ ((grow&8)<<2)  (bank split)
        *(i32x4*)(xt + b + ((grow * 32 + gh) ^ ((grow & 8) << 2))) = G[n];

        unsigned ga[8], gb[8];
        #pragma unroll
        for (int j = 0; j < 8; ++j) {
            const int e0 = kh8 + j, e1 = e0 + 16;
            ga[j] = *(const unsigned short*)(xt + b + ((e0 * 32 + dcl * 2) ^ ((e0 & 8) << 2)));
            gb[j] = *(const unsigned short*)(xt + b + ((e1 * 32 + dcl * 2) ^ ((e1 & 8) << 2)));
        }

        const int nl = w * NPW + n;
        const int el = nl * DEG + kh8;
        const short8 raw0 = *(const short8*)(kvrow + el);
        const short8 raw1 = *(const short8*)(kvrow + el + 16);
        const unsigned fill = (m == 2) ? 0x3F803F80u : 0u;
        const short8 af0 = (m < 2) ? raw0 : mk8(fill, fill, fill, fill);
        const short8 af1 = (m < 2) ? raw1 : mk8(fill, fill, fill, fill);
        const short8 bf0 = mk8(pk(ga[0], ga[1]), pk(ga[2], ga[3]),
                               pk(ga[4], ga[5]), pk(ga[6], ga[7]));
        const short8 bf1 = mk8(pk(gb[0], gb[1]), pk(gb[2], gb[3]),
                               pk(gb[4], gb[5]), pk(gb[6], gb[7]));

        float16 acc;
        #pragma unroll
        for (int r = 0; r < 16; ++r) acc[r] = 0.f;
        acc = __builtin_amdgcn_mfma_f32_32x32x16_bf16(af0, bf0, acc, 0, 0, 0);
        acc = __builtin_amdgcn_mfma_f32_32x32x16_bf16(af1, bf1, acc, 0, 0, 0);

        if (kh == 0 && m < 16) {
            const float sm = acc[2] * (1.f / 32.f);
            const float pv = bf2f(xv[n]) - sm;
            const size_t pr = (size_t)(base + nl) * 32;
            __builtin_nontemporal_store(f2bf(acc[0] + pv), &prew[pr + m]);
            __builtin_nontemporal_store(f2bf(acc[1] + pv), &prew[pr + 16 + m]);
        }
    }
}

// ================= pass B: hi features (d16-23, slice 1.6MB) + MLP =================
__global__ __launch_bounds__(TPB, 4) void gnnB(
    const unsigned short* __restrict__ xhi,   // [N,8] bf16 (16B rows)
    const int*            __restrict__ ei,
    const float*          __restrict__ kv,
    const unsigned short* __restrict__ prew,  // [N,32] from pass A
    const float*          __restrict__ W,     // [64,48]
    float*                __restrict__ out)   // [N,64]
{
    __shared__ int            ei_s[NPB * DEG];       // src*16 byte offsets
    __shared__ unsigned short kv_s[2 * NPB * DEG];
    __shared__ unsigned short xt_s[4][768];          // per-wave [2 buf][32 e][12 u16]
    __shared__ unsigned short pre_s[NPB * 16];       // [32 nodes][a0hi(8)|a1hi(8)]

    const int t    = threadIdx.x;
    const int lane = t & 63;
    const int w    = t >> 6;
    const int m    = lane & 31;
    const int kh   = lane >> 5;
    const int kh8  = kh * 8;
    const int base = blockIdx.x * NPB;
    const int dcl  = (m < 8) ? m : 7;
    const char* xc = (const char*)xhi;
    const int grow = lane >> 1;          // gather row (edge 0..31)
    const int gh   = (lane & 1) * 8;     // 8B half of 16B row
    char* xt = (char*)&xt_s[w][0];

    {
        const size_t eb = (size_t)base * DEG;
        i32x4 ev = __builtin_nontemporal_load(((const i32x4*)(ei + eb)) + t);
        ev.x <<= 4; ev.y <<= 4; ev.z <<= 4; ev.w <<= 4;
        ((i32x4*)ei_s)[t] = ev;
        const f32x4 c0 = __builtin_nontemporal_load(((const f32x4*)(kv + eb)) + t);
        const f32x4 c1 = __builtin_nontemporal_load(((const f32x4*)(kv + EE + eb)) + t);
        u16x4 u0, u1;
        u0.x = f2bf(c0.x); u0.y = f2bf(c0.y); u0.z = f2bf(c0.z); u0.w = f2bf(c0.w);
        u1.x = f2bf(c1.x); u1.y = f2bf(c1.y); u1.z = f2bf(c1.z); u1.w = f2bf(c1.w);
        ((u16x4*)kv_s)[t] = u0;
        ((u16x4*)(kv_s + NPB * DEG))[t] = u1;
    }
    __syncthreads();

    const unsigned short* kvrow = kv_s + (m & 1) * (NPB * DEG);

    // phase-2 pre-lo prefetch (waves 0,1): issued first, oldest in VMEM queue
    i32x4 wsA, wsB, wsC;
    if (w < 2) {
        const unsigned short* pr = prew + (size_t)(base + m) * 32;
        wsA = *(const i32x4*)(pr + kh8);       // K 0-15 slice
        wsB = *(const i32x4*)(pr + 16);        // a1 d0-7  (kh1 of kc1)
        wsC = *(const i32x4*)(pr + 24);        // a1 d8-15 (kh0 of kc2)
    }

    i32x2 G[NPW];
    unsigned xv[NPW];

    #pragma unroll
    for (int n = 0; n < NPW; ++n)
        xv[n] = xhi[(size_t)(base + w * NPW + n) * 8 + dcl];

    #pragma unroll
    for (int n = 0; n < NPW; ++n) {
        const int off = ei_s[(w * NPW + n) * DEG + grow];
        G[n] = *(const i32x2*)(xc + (unsigned)(off + gh));
    }

    #pragma unroll
    for (int n = 0; n < NPW; ++n) {
        const int b = (n & 1) * 768;
        // write node tile: row grow, 24B row stride (bank-staggered)
        *(i32x2*)(xt + b + grow * 24 + gh) = G[n];

        unsigned ga[8], gb[8];
        #pragma unroll
        for (int j = 0; j < 8; ++j) {
            const int e0 = kh8 + j, e1 = e0 + 16;
            ga[j] = *(const unsigned short*)(xt + b + e0 * 24 + dcl * 2);
            gb[j] = *(const unsigned short*)(xt + b + e1 * 24 + dcl * 2);
        }

        const int nl = w * NPW + n;
        const int el = nl * DEG + kh8;
        const short8 raw0 = *(const short8*)(kvrow + el);
        const short8 raw1 = *(const short8*)(kvrow + el + 16);
        const unsigned fill = (m == 2) ? 0x3F803F80u : 0u;
        const short8 af0 = (m < 2) ? raw0 : mk8(fill, fill, fill, fill);
        const short8 af1 = (m < 2) ? raw1 : mk8(fill, fill, fill, fill);
        const short8 bf0 = mk8(pk(ga[0], ga[1]), pk(ga[2], ga[3]),
                               pk(ga[4], ga[5]), pk(ga[6], ga[7]));
        const short8 bf1 = mk8(pk(gb[0], gb[1]), pk(gb[2], gb[3]),
                               pk(gb[4], gb[5]), pk(gb[6], gb[7]));

        float16 acc;
        #pragma unroll
        for (int r = 0; r < 16; ++r) acc[r] = 0.f;
        acc = __builtin_amdgcn_mfma_f32_32x32x16_bf16(af0, bf0, acc, 0, 0, 0);
        acc = __builtin_amdgcn_mfma_f32_32x32x16_bf16(af1, bf1, acc, 0, 0, 0);

        if (kh == 0 && m < 8) {
            const float sm = acc[2] * (1.f / 32.f);
            const float pv = bf2f(xv[n]) - sm;
            pre_s[nl * 16 + m]     = f2bf(acc[0] + pv);
            pre_s[nl * 16 + 8 + m] = f2bf(acc[1] + pv);
        }
    }
    __syncthreads();

    // ---- phase 2: out(32x64) = pre(32x48) @ W^T, waves 0,1
    if (w < 2) {
        const int h = w * 32 + m;
        union { i32x4 v; short8 s; } uA, uB, uC;
        uA.v = wsA; uB.v = wsB; uC.v = wsC;

        float16 acc;
        #pragma unroll
        for (int r = 0; r < 16; ++r) acc[r] = 0.f;

        #pragma unroll
        for (int kc = 0; kc < 3; ++kc) {
            short8 af;
            if (kc == 0) {
                af = uA.s;                                        // a0 d0-15
            } else if (kc == 1) {
                const short8 l = *(const short8*)(pre_s + m * 16);    // a0 hi
                af = (kh == 0) ? l : uB.s;                        // | a1 d0-7
            } else {
                const short8 l = *(const short8*)(pre_s + m * 16 + 8);// a1 hi
                af = (kh == 0) ? uC.s : l;                        // a1 d8-15 |
            }
            const float* wr = W + h * 48 + kc * 16 + kh8;
            const f32x4 wA = ((const f32x4*)wr)[0];
            const f32x4 wB = ((const f32x4*)wr)[1];
            const short8 bf = mk8(pk(f2bf(wA.x), f2bf(wA.y)), pk(f2bf(wA.z), f2bf(wA.w)),
                                  pk(f2bf(wB.x), f2bf(wB.y)), pk(f2bf(wB.z), f2bf(wB.w)));
            acc = __builtin_amdgcn_mfma_f32_32x32x16_bf16(af, bf, acc, 0, 0, 0);
        }

        #pragma unroll
        for (int r = 0; r < 16; ++r) {
            const int row = (r & 3) + 8 * (r >> 2) + 4 * kh;
            __builtin_nontemporal_store(acc[r], &out[(size_t)(base + row) * HH + h]);
        }
    }
}

extern "C" void kernel_launch(void* const* d_in, const int* in_sizes, int n_in,
                              void* d_out, int out_size, void* d_ws, size_t ws_size,
                              hipStream_t stream) {
    const float* x  = (const float*)d_in[0];
    const int*   ei = (const int*)d_in[1];
    const float* kv = (const float*)d_in[2];
    const float* W  = (const float*)d_in[3];
    float* out = (float*)d_out;

    unsigned short* xlo  = (unsigned short*)d_ws;        // 3.2 MB
    unsigned short* xhi  = xlo + (size_t)NN * 16;        // 1.6 MB
    unsigned short* prew = xhi + (size_t)NN * 8;         // 6.4 MB  (total 11.2 MB)

    const int n6 = NN * 6;                               // 600000 f32x4 chunks
    xcvt2<<<(n6 + 255) / 256, 256, 0, stream>>>(x, xlo, xhi, n6);

    const int grid = NN / NPB;                           // 3125, exact
    gnnA<<<grid, TPB, 0, stream>>>(xlo, ei, kv, prew);
    gnnB<<<grid, TPB, 0, stream>>>(xhi, ei, kv, prew, W, out);
}

// Round 8
// 129.717 us; speedup vs baseline: 1.1526x; 1.1526x over previous
//
#include <hip/hip_runtime.h>

// net_86698209837440: N=100000, DEG=32 (edges sorted by tgt, deg==32), D=24, NK=2, H=64.
// R15 = R13 single-pass (tr-read interp B, verified) with OCCUPANCY raised.
// R14's feature-split A/B showed per-request cost ~10-12.5ns nearly invariant
// to width/inst-count/depth/L2-residency => concurrency-bound (MSHR model).
// Only untested lever: blocks/CU. Changes vs R13:
//  - per-wave xs tile 4KB -> 2KB (single node, 2 gather insts/node, depth-2
//    node prefetch). LDS 27.5 -> 19.5 KB => 8 blocks/CU (was 5).
//  - __launch_bounds__(256,6): 24 waves/CU target (VGPR cap 85).
// Math/mapping byte-identical to R13 (region j*1024 = edges 16j..16j+15,
// same wbase / rdoff / tr offsets {0,512,1024,1536}, kv A-frags, epilogue).

#define NN   100000
#define DEG  32
#define EE   (NN * DEG)
#define DD   24
#define HH   64
#define NPB  32            // nodes per block; 100000 = 3125 * 32 exact
#define TPB  256
#define NPW  8             // nodes per wave
#define PST  56            // pre_s row stride (ushorts)
#define XRU  32            // padded xb row length in u16 (64 bytes)

typedef __attribute__((ext_vector_type(8)))  short short8;
typedef __attribute__((ext_vector_type(16))) float float16;
typedef __attribute__((ext_vector_type(4)))  float f32x4;
typedef __attribute__((ext_vector_type(4)))  int   i32x4;
typedef __attribute__((ext_vector_type(4)))  unsigned short u16x4;

__device__ __forceinline__ unsigned short f2bf(float f) {
    union { float f; unsigned u; } v; v.f = f;
    unsigned r = v.u + 0x7fffu + ((v.u >> 16) & 1u);   // RNE
    return (unsigned short)(r >> 16);
}

__device__ __forceinline__ float bf2f(unsigned u) {
    union { unsigned i; float f; } v; v.i = u << 16; return v.f;
}

// lo16(a) -> low half, lo16(b) -> high half, one v_perm_b32
__device__ __forceinline__ unsigned pk(unsigned a, unsigned b) {
    return __builtin_amdgcn_perm(b, a, 0x05040100u);
}

__device__ __forceinline__ short8 mk8(unsigned u0, unsigned u1, unsigned u2, unsigned u3) {
    union { unsigned u[4]; short8 s; } p;
    p.u[0] = u0; p.u[1] = u1; p.u[2] = u2; p.u[3] = u3;
    return p.s;
}

// ---- pre-pass: x fp32 [N][24] -> bf16 padded [N][32] (64B rows), coalesced
// writes over the full padded table (pad chunks 6,7 write zeros).
__global__ void xcvt(const float* __restrict__ x, unsigned short* __restrict__ xb, int n8) {
    int c = blockIdx.x * blockDim.x + threadIdx.x;   // u16x4 chunk in padded table
    if (c < n8) {
        const int row = c >> 3;
        const int pos = c & 7;
        u16x4 o = (u16x4){0, 0, 0, 0};
        if (pos < 6) {
            f32x4 v = __builtin_nontemporal_load(((const f32x4*)x) + row * 6 + pos);
            o.x = f2bf(v.x); o.y = f2bf(v.y); o.z = f2bf(v.z); o.w = f2bf(v.w);
        }
        ((u16x4*)xb)[c] = o;
    }
}

__global__ __launch_bounds__(TPB, 6) void gnn(
    const unsigned short* __restrict__ xb,   // [N,32] bf16 padded (gather table)
    const int*            __restrict__ ei,   // [2,E]; row 0 = src
    const float*          __restrict__ kv,   // [2,E]
    const float*          __restrict__ W,    // [64,48]
    float*                __restrict__ out)  // [N,64]
{
    __shared__ int            ei_s[NPB * DEG];       // 4 KB: src*64 byte offsets
    __shared__ unsigned short kv_s[2 * NPB * DEG];   // 4 KB bf16 kvals
    __shared__ unsigned short pre_s[NPB * PST];      // 3.5 KB bf16 pre rows
    __shared__ __align__(128) unsigned short xs_s[4][1024];  // 8 KB: 2KB/wave tile

    const int t    = threadIdx.x;
    const int lane = t & 63;
    const int w    = t >> 6;
    const int m    = lane & 31;      // A-row / B-col / C-col
    const int kh   = lane >> 5;      // K-half
    const int kh8  = kh * 8;
    const int base = blockIdx.x * NPB;
    const int dclamp = (m < DD) ? m : (DD - 1);
    const char* xbc  = (const char*)xb;

    // gather geometry (per lane): inst j covers rows j*16+er, chunk q16 of 64B row
    const int er   = lane >> 2;                        // row-slot within 16
    const int q16  = (lane & 3) * 16;                  // 16B chunk within row
    char* xsb = (char*)&xs_s[w][0];                    // wave-private 2KB tile

    // write remap into tr-native layout (verified R13): within 1KB 16-row region
    const int wbase = ((er >> 2) & 1) * 512 + ((er >> 3) & 1) * 256
                    + (er & 3) * 32
                    + ((lane & 3) >> 1) * 128 + (lane & 1) * 16;
    // tr-read per-lane offset (slot-granular): col slot (lane&15)*8, group (lane>>4)*128
    const int rdoff = (lane & 15) * 8 + (lane >> 4) * 128;
    const unsigned va_base = (unsigned)(size_t)(xsb) + (unsigned)rdoff;

    // ---- cooperative staging: ei row0 (pre-scaled *64) + both kv rows (bf16)
    {
        const size_t eb = (size_t)base * DEG;        // 1024 edges per block
        i32x4 ev = __builtin_nontemporal_load(((const i32x4*)(ei + eb)) + t);
        ev.x <<= 6; ev.y <<= 6; ev.z <<= 6; ev.w <<= 6;
        ((i32x4*)ei_s)[t] = ev;
        const f32x4 c0 = __builtin_nontemporal_load(((const f32x4*)(kv + eb)) + t);
        const f32x4 c1 = __builtin_nontemporal_load(((const f32x4*)(kv + EE + eb)) + t);
        u16x4 u0, u1;
        u0.x = f2bf(c0.x); u0.y = f2bf(c0.y); u0.z = f2bf(c0.z); u0.w = f2bf(c0.w);
        u1.x = f2bf(c1.x); u1.y = f2bf(c1.y); u1.z = f2bf(c1.z); u1.w = f2bf(c1.w);
        ((u16x4*)kv_s)[t] = u0;
        ((u16x4*)(kv_s + NPB * DEG))[t] = u1;
    }
    __syncthreads();

    // ================= Phase 1: per-node pipeline, depth-2 prefetch =================
    const unsigned short* kvrow = kv_s + (m & 1) * (NPB * DEG);  // m=0 -> k0, m=1 -> k1

    i32x4 G[2][2];          // 16 VGPR of in-flight gathered lines
    unsigned xv8[NPW];      // epilogue x values, one per node

    #define GATHER_NODE(n, sl) do {                                            \
        const int eb_ = (w * NPW + (n)) * DEG;                                 \
        const int o0_ = ei_s[eb_ + er];                                        \
        const int o1_ = ei_s[eb_ + 16 + er];                                   \
        G[sl][0] = *(const i32x4*)(xbc + (unsigned)(o0_ + q16));               \
        G[sl][1] = *(const i32x4*)(xbc + (unsigned)(o1_ + q16));               \
    } while (0)

    // write node tile: region j*1024 holds edges 16j..16j+15 (tr-native layout)
    #define WRITE_NODE(sl) do {                                                \
        *(i32x4*)(xsb + 0 * 1024 + wbase) = G[sl][0];                          \
        *(i32x4*)(xsb + 1 * 1024 + wbase) = G[sl][1];                          \
    } while (0)

    #define COMPUTE_NODE(n) do {                                               \
        const int nl_ = w * NPW + (n);                                         \
        unsigned long long t0_, t1_, t2_, t3_;                                 \
        asm volatile(                                                          \
            "s_waitcnt lgkmcnt(0)\n\t"                                         \
            "ds_read_b64_tr_b16 %0, %4 offset:0\n\t"                           \
            "ds_read_b64_tr_b16 %1, %4 offset:512\n\t"                         \
            "ds_read_b64_tr_b16 %2, %4 offset:1024\n\t"                        \
            "ds_read_b64_tr_b16 %3, %4 offset:1536\n\t"                        \
            "s_waitcnt lgkmcnt(0)"                                             \
            : "=&v"(t0_), "=&v"(t1_), "=&v"(t2_), "=&v"(t3_)                   \
            : "v"(va_base) : "memory");                                        \
        union { unsigned long long q[2]; short8 s; } b0u_, b1u_;               \
        b0u_.q[0] = t0_; b0u_.q[1] = t1_;                                      \
        b1u_.q[0] = t2_; b1u_.q[1] = t3_;                                      \
        const int el_ = nl_ * DEG + kh8;                                       \
        const short8 raw0_ = *(const short8*)(kvrow + el_);                    \
        const short8 raw1_ = *(const short8*)(kvrow + el_ + 16);               \
        const unsigned fill_ = (m == 2) ? 0x3F803F80u : 0u;                    \
        const short8 af0_ = (m < 2) ? raw0_ : mk8(fill_, fill_, fill_, fill_); \
        const short8 af1_ = (m < 2) ? raw1_ : mk8(fill_, fill_, fill_, fill_); \
        float16 acc_;                                                          \
        _Pragma("unroll")                                                      \
        for (int r = 0; r < 16; ++r) acc_[r] = 0.f;                            \
        acc_ = __builtin_amdgcn_mfma_f32_32x32x16_bf16(af0_, b0u_.s, acc_, 0, 0, 0); \
        acc_ = __builtin_amdgcn_mfma_f32_32x32x16_bf16(af1_, b1u_.s, acc_, 0, 0, 0); \
        if (kh == 0 && m < DD) {                                               \
            const float sm_ = acc_[2] * (1.f / 32.f);                          \
            const float pv_ = bf2f(xv8[n]) - sm_;                              \
            pre_s[nl_ * PST + m]      = f2bf(acc_[0] + pv_);                   \
            pre_s[nl_ * PST + 24 + m] = f2bf(acc_[1] + pv_);                   \
        }                                                                      \
    } while (0)

    // epilogue xv loads first (oldest in queue -> complete early)
    #pragma unroll
    for (int nn = 0; nn < NPW; ++nn)
        xv8[nn] = xb[(size_t)(base + w * NPW + nn) * XRU + dclamp];

    GATHER_NODE(0, 0);

    #pragma unroll
    for (int n = 0; n < NPW; ++n) {
        const int sl = n & 1;
        if (n < NPW - 1) GATHER_NODE(n + 1, sl ^ 1);   // keep next node in flight
        WRITE_NODE(sl);          // counted vmcnt (2 newer loads outstanding)
        COMPUTE_NODE(n);
    }
    #undef GATHER_NODE
    #undef WRITE_NODE
    #undef COMPUTE_NODE
    __syncthreads();

    // ================= Phase 2: out(32x64) = pre(32x48) @ W^T, waves 0,1 =================
    if (w < 2) {
        const int h = w * 32 + m;

        float16 acc;
        #pragma unroll
        for (int r = 0; r < 16; ++r) acc[r] = 0.f;

        #pragma unroll
        for (int kc = 0; kc < 3; ++kc) {
            const int c0 = kc * 16 + kh8;
            const short8 af = *(const short8*)(pre_s + m * PST + c0);
            const float* wr = W + h * 48 + c0;
            const f32x4 wA = ((const f32x4*)wr)[0];
            const f32x4 wB = ((const f32x4*)wr)[1];
            const short8 bf = mk8(pk(f2bf(wA.x), f2bf(wA.y)), pk(f2bf(wA.z), f2bf(wA.w)),
                                  pk(f2bf(wB.x), f2bf(wB.y)), pk(f2bf(wB.z), f2bf(wB.w)));
            acc = __builtin_amdgcn_mfma_f32_32x32x16_bf16(af, bf, acc, 0, 0, 0);
        }

        #pragma unroll
        for (int r = 0; r < 16; ++r) {
            const int row = (r & 3) + 8 * (r >> 2) + 4 * kh;   // node within block
            __builtin_nontemporal_store(acc[r], &out[(size_t)(base + row) * HH + h]);
        }
    }
}

extern "C" void kernel_launch(void* const* d_in, const int* in_sizes, int n_in,
                              void* d_out, int out_size, void* d_ws, size_t ws_size,
                              hipStream_t stream) {
    const float* x  = (const float*)d_in[0];
    const int*   ei = (const int*)d_in[1];
    const float* kv = (const float*)d_in[2];
    const float* W  = (const float*)d_in[3];
    float* out = (float*)d_out;

    unsigned short* xb = (unsigned short*)d_ws;            // 6.4 MB scratch (padded)
    const int n8 = NN * 8;                                 // 800000 u16x4 chunks
    xcvt<<<(n8 + 255) / 256, 256, 0, stream>>>(x, xb, n8);

    const int grid = NN / NPB;                             // 3125, exact
    gnn<<<grid, TPB, 0, stream>>>(xb, ei, kv, W, out);
}